// Round 3
// baseline (684.593 us; speedup 1.0000x reference)
//
#include <hip/hip_runtime.h>
#include <hip/hip_bf16.h>

#define D_MODEL 1024
#define BATCH 8
#define SEQ 4096
#define MROWS (BATCH*SEQ)   // 32768
#define NC 64               // number of scan chunks
#define CL 64               // chunk length (NC*CL == SEQ)
#define BK 64
#define NKT (D_MODEL/BK)    // 16 K-tiles
#define HTE (128*64)        // half-tile elements (bf16)

typedef __attribute__((ext_vector_type(4))) float f32x4;
typedef __attribute__((ext_vector_type(8))) short s16x8;

__device__ __forceinline__ unsigned short f2bf(float f){
  union { float f; unsigned int u; } v; v.f = f;
  return (unsigned short)((v.u + 0x7fffu + ((v.u >> 16) & 1u)) >> 16);
}
__device__ __forceinline__ float bf2f(unsigned int bits){
  union { unsigned int u; float f; } v; v.u = bits << 16; return v.f;
}

__device__ __forceinline__ void gload16(const void* g, void* l){
  __builtin_amdgcn_global_load_lds(
      (const __attribute__((address_space(1))) unsigned int*)g,
      (__attribute__((address_space(3))) unsigned int*)l, 16, 0, 0);
}

// Stage one 128x64-bf16 half-tile: all 8 waves, 2 gload16/thread.
// Content-swizzle (T2): source chunk XOR'd so ds_read side can XOR too,
// LDS dest stays linear (global_load_lds constraint, rule #21).
__device__ __forceinline__ void stage_half(const unsigned short* __restrict__ g, int row0,
                                           unsigned short* lds, int kt, int wid, int lane){
  #pragma unroll
  for (int s=0;s<2;s++){
    const int ob = s*512 + wid*64;          // wave-uniform chunk base
    const int o  = ob + lane;
    const int r  = o >> 3;                  // row 0..127
    const int c  = ((o & 7) ^ (r & 7)) * 16;
    gload16((const char*)g + (size_t)(row0 + r)*(D_MODEL*2) + (size_t)kt*128 + c,
            (char*)lds + (size_t)ob*16);
  }
}

// ---------------- prep: x -> bf16 ----------------
__global__ __launch_bounds__(256)
void prep_x_kernel(const float* __restrict__ x, unsigned short* __restrict__ xb, int n4){
  int i = blockIdx.x*256 + threadIdx.x;
  int stride = gridDim.x*256;
  for (; i < n4; i += stride){
    float4 v = ((const float4*)x)[i];
    ushort4 o;
    o.x = f2bf(v.x); o.y = f2bf(v.y); o.z = f2bf(v.z); o.w = f2bf(v.w);
    ((ushort4*)xb)[i] = o;
  }
}

// ---------------- prep: weights -> bf16, decay ----------------
__global__ __launch_bounds__(256)
void prep_w_kernel(const float* __restrict__ Wi, const float* __restrict__ Wg,
                   const float* __restrict__ Wo, const float* __restrict__ ld,
                   unsigned short* __restrict__ Wib, unsigned short* __restrict__ Wgb,
                   unsigned short* __restrict__ Wob, float* __restrict__ decay){
  int i = blockIdx.x*256 + threadIdx.x;   // grid covers D*D/4 exactly
  {
    float4 a = ((const float4*)Wi)[i]; ushort4 o;
    o.x=f2bf(a.x); o.y=f2bf(a.y); o.z=f2bf(a.z); o.w=f2bf(a.w); ((ushort4*)Wib)[i]=o;
    a = ((const float4*)Wg)[i];
    o.x=f2bf(a.x); o.y=f2bf(a.y); o.z=f2bf(a.z); o.w=f2bf(a.w); ((ushort4*)Wgb)[i]=o;
    a = ((const float4*)Wo)[i];
    o.x=f2bf(a.x); o.y=f2bf(a.y); o.z=f2bf(a.z); o.w=f2bf(a.w); ((ushort4*)Wob)[i]=o;
  }
  if (i < D_MODEL){
    float v = ld[i];
    float sp = fmaxf(v, 0.f) + log1pf(expf(-fabsf(v)));   // stable softplus
    decay[i] = sp + 1e-4f;
  }
}

// ============ 256x256 8-phase GEMM (T1+T2+T3+T4+T5), C = A * B^T ============
// MODE 0: U-pass   -> ubw = bf16(acc + b_in)
// MODE 1: G-pass   -> pack = {bf16(drive), bf16(1-lambda)} from acc,ubr,delta
// MODE 2: out-pass -> y = acc + b_out (f32)
//
// Phase schedule per iteration (kt = 2*it), hazard-verified:
//  ph0: read B[0],A[0]q0 | stage A[1]h0<-kt+1
//  ph1: read A[0]q1      | stage A[1]h1<-kt+1
//  ph2: read A[0]q2      | stage B[0]h0<-kt+2
//  ph3: read A[0]q3      | stage B[0]h1<-kt+2 | vmcnt(4)  (guards ph4 reads)
//  ph4: read B[1],A[1]q0 | stage A[0]h0<-kt+2
//  ph5: read A[1]q1      | stage A[0]h1<-kt+2
//  ph6: read A[1]q2      | stage B[1]h0<-kt+3
//  ph7: read A[1]q3      | stage B[1]h1<-kt+3 | vmcnt(4)  (guards next ph0)
// Every stage overwrites a slot whose last ds-read is >=1 barrier earlier.
// vmcnt(4) = 2 half-tiles in flight; never drained to 0 in the main loop.

#define PHASE(d, q, SB_, SD, SH, KOFF, VM) do {                                   \
  if ((q) == 0) {                                                                 \
    _Pragma("unroll")                                                             \
    for (int n=0;n<4;n++){                                                        \
      const int rl = (wcn&1)*64 + n*16 + (lane&15);                               \
      _Pragma("unroll")                                                           \
      for (int ks=0;ks<2;ks++){                                                   \
        const int ch = (ks*4 + (lane>>4)) ^ (rl&7);                               \
        bf[n][ks] = *(const s16x8*)((const char*)&sB[d][wcn>>1][0] + rl*128 + ch*16); \
      }                                                                           \
    }                                                                             \
  }                                                                               \
  _Pragma("unroll")                                                               \
  for (int mi=0;mi<2;mi++){                                                       \
    const int rl = ((q)*2+mi)*16 + (lane&15);                                     \
    _Pragma("unroll")                                                             \
    for (int ks=0;ks<2;ks++){                                                     \
      const int ch = (ks*4 + (lane>>4)) ^ (rl&7);                                 \
      af[mi][ks] = *(const s16x8*)((const char*)&sA[d][wr][0] + rl*128 + ch*16);  \
    }                                                                             \
  }                                                                               \
  { int skt = kt + (KOFF); if (skt > NKT-1) skt = NKT-1;                          \
    if (SB_) stage_half(Bglob, bcol + (SH)*128, &sB[SD][SH][0], skt, wid, lane);  \
    else     stage_half(Aglob, brow + (SH)*128, &sA[SD][SH][0], skt, wid, lane); }\
  if (VM) asm volatile("s_waitcnt vmcnt(4)" ::: "memory");                        \
  __builtin_amdgcn_s_barrier();                                                   \
  asm volatile("s_waitcnt lgkmcnt(0)" ::: "memory");                              \
  __builtin_amdgcn_sched_barrier(0);                                              \
  __builtin_amdgcn_s_setprio(1);                                                  \
  _Pragma("unroll")                                                               \
  for (int ks=0;ks<2;ks++)                                                        \
    _Pragma("unroll")                                                             \
    for (int mi=0;mi<2;mi++)                                                      \
      _Pragma("unroll")                                                           \
      for (int n=0;n<4;n++)                                                       \
        acc[(q)*2+mi][n] = __builtin_amdgcn_mfma_f32_16x16x32_bf16(               \
            af[mi][ks], bf[n][ks], acc[(q)*2+mi][n], 0,0,0);                      \
  __builtin_amdgcn_s_setprio(0);                                                  \
  __builtin_amdgcn_s_barrier();                                                   \
} while(0)

template<int MODE>
__global__ __launch_bounds__(512, 2)
void gemm8_kernel(const unsigned short* __restrict__ Aglob,
                  const unsigned short* __restrict__ Bglob,
                  const float* __restrict__ bias,
                  const float* __restrict__ decay,
                  const float* __restrict__ delta,
                  const unsigned short* __restrict__ ubr,
                  unsigned short* __restrict__ ubw,
                  unsigned int* __restrict__ pack,
                  float* __restrict__ y)
{
  __shared__ unsigned short sA[2][2][HTE];   // [dbuf][half][128*64]
  __shared__ unsigned short sB[2][2][HTE];
  const int tid  = threadIdx.x;
  const int lane = tid & 63;
  const int wid  = tid >> 6;     // 0..7
  const int wr   = wid >> 2;     // M half 0..1
  const int wcn  = wid & 3;      // N quarter 0..3
  // XCD-chunked bijective swizzle: 512 blocks = 8 XCDs x 64
  const int bid  = blockIdx.x;
  const int swz  = ((bid & 7) << 6) | (bid >> 3);
  const int bcol = (swz & 3) * 256;
  const int brow = (swz >> 2) * 256;

  const f32x4 zero = {0.f,0.f,0.f,0.f};
  f32x4 acc[8][4];
  #pragma unroll
  for (int m=0;m<8;m++)
    #pragma unroll
    for (int n=0;n<4;n++) acc[m][n]=zero;

  // prologue: B[0]<-0, A[0]<-0, B[1]<-1 ; leave B[1] (4 loads) in flight
  stage_half(Bglob, bcol+0,   &sB[0][0][0], 0, wid, lane);
  stage_half(Bglob, bcol+128, &sB[0][1][0], 0, wid, lane);
  stage_half(Aglob, brow+0,   &sA[0][0][0], 0, wid, lane);
  stage_half(Aglob, brow+128, &sA[0][1][0], 0, wid, lane);
  stage_half(Bglob, bcol+0,   &sB[1][0][0], 1, wid, lane);
  stage_half(Bglob, bcol+128, &sB[1][1][0], 1, wid, lane);
  asm volatile("s_waitcnt vmcnt(4)" ::: "memory");
  __builtin_amdgcn_s_barrier();

  for (int it = 0; it < NKT/2; ++it){
    const int kt = it*2;
    s16x8 bf[4][2];
    s16x8 af[2][2];
    PHASE(0,0, 0,1,0, 1, 0);
    PHASE(0,1, 0,1,1, 1, 0);
    PHASE(0,2, 1,0,0, 2, 0);
    PHASE(0,3, 1,0,1, 2, 1);
    PHASE(1,0, 0,0,0, 2, 0);
    PHASE(1,1, 0,0,1, 2, 0);
    PHASE(1,2, 1,1,0, 3, 0);
    PHASE(1,3, 1,1,1, 3, 1);
  }

  asm volatile("s_waitcnt vmcnt(0)" ::: "memory");  // drain tail stages

  #pragma unroll
  for (int n=0;n<4;n++){
    const int col = bcol + wcn*64 + n*16 + (lane & 15);
    const float vb = bias[col];
    float dc = 0.f;
    if constexpr (MODE==1) dc = decay[col];
    #pragma unroll
    for (int m=0;m<8;m++){
      #pragma unroll
      for (int j=0;j<4;j++){
        const int row = brow + wr*128 + m*16 + ((lane>>4)*4) + j;
        const size_t idx = (size_t)row*D_MODEL + col;
        const float v = acc[m][n][j] + vb;
        if constexpr (MODE==0){
          ubw[idx] = f2bf(v);
        } else if constexpr (MODE==1){
          const float u = bf2f((unsigned int)ubr[idx]);
          const float g = 1.f/(1.f + __expf(-v));
          const float dt = fmaxf(delta[idx], 1e-4f);
          const float lam = __expf(-dc*dt);
          const float omla = 1.f - lam;
          const float drv = omla * g * u;
          pack[idx] = ((unsigned int)f2bf(drv) << 16) | (unsigned int)f2bf(omla);
        } else {
          y[idx] = v;
        }
      }
    }
  }
}

// ---------------- scan pass A: per-chunk (A = prod lam, B = local scan) ----------------
__global__ __launch_bounds__(256)
void scan_passA(const unsigned int* __restrict__ pack, float* __restrict__ cA, float* __restrict__ cB){
  const int d0 = (blockIdx.x*256 + threadIdx.x)*2;   // gridDim.x = D/512 = 2
  const int c = blockIdx.y, b = blockIdx.z;
  size_t base = ((size_t)b*SEQ + (size_t)c*CL)*D_MODEL + d0;
  float A0=1.f, A1=1.f, s0=0.f, s1=0.f;
  #pragma unroll 8
  for (int t=0;t<CL;t++){
    uint2 p = *(const uint2*)(pack + base + (size_t)t*D_MODEL);
    float om0 = bf2f(p.x & 0xffffu), dr0 = bf2f(p.x >> 16);
    float om1 = bf2f(p.y & 0xffffu), dr1 = bf2f(p.y >> 16);
    float l0 = 1.f - om0, l1 = 1.f - om1;
    A0 *= l0; A1 *= l1;
    s0 = fmaf(l0, s0, dr0);
    s1 = fmaf(l1, s1, dr1);
  }
  const size_t ci = ((size_t)b*NC + c)*D_MODEL + d0;
  *(float2*)(cA+ci) = make_float2(A0,A1);
  *(float2*)(cB+ci) = make_float2(s0,s1);
}

// ---------------- scan pass B: sequential chunk combine + final_state ----------------
__global__ __launch_bounds__(256)
void scan_passB(const float* __restrict__ cA, const float* __restrict__ cB,
                float* __restrict__ cS, float* __restrict__ fstate){
  const int d0 = (blockIdx.x*256 + threadIdx.x)*2;  // gridDim.x = 2
  const int b = blockIdx.y;
  float s0=0.f, s1=0.f;
  for (int c=0;c<NC;c++){
    const size_t ci = ((size_t)b*NC + c)*D_MODEL + d0;
    *(float2*)(cS+ci) = make_float2(s0,s1);
    float2 a  = *(const float2*)(cA+ci);
    float2 bb = *(const float2*)(cB+ci);
    s0 = fmaf(a.x, s0, bb.x);
    s1 = fmaf(a.y, s1, bb.y);
  }
  *(float2*)(fstate + (size_t)b*D_MODEL + d0) = make_float2(s0,s1);
}

// ---------------- scan pass C: re-scan chunks, emit states (bf16) ----------------
__global__ __launch_bounds__(256)
void scan_passC(const unsigned int* __restrict__ pack, const float* __restrict__ cS,
                unsigned short* __restrict__ statesb){
  const int d0 = (blockIdx.x*256 + threadIdx.x)*2;
  const int c = blockIdx.y, b = blockIdx.z;
  float2 sv = *(const float2*)(cS + ((size_t)b*NC + c)*D_MODEL + d0);
  float s0 = sv.x, s1 = sv.y;
  size_t base = ((size_t)b*SEQ + (size_t)c*CL)*D_MODEL + d0;
  #pragma unroll 8
  for (int t=0;t<CL;t++){
    uint2 p = *(const uint2*)(pack + base + (size_t)t*D_MODEL);
    float om0 = bf2f(p.x & 0xffffu), dr0 = bf2f(p.x >> 16);
    float om1 = bf2f(p.y & 0xffffu), dr1 = bf2f(p.y >> 16);
    s0 = fmaf(-om0, s0, s0) + dr0;   // s = (1-om)*s + dr, decay-precise
    s1 = fmaf(-om1, s1, s1) + dr1;
    unsigned int w = ((unsigned int)f2bf(s1) << 16) | (unsigned int)f2bf(s0);
    *(unsigned int*)(statesb + base + (size_t)t*D_MODEL) = w;
  }
}

// ---------------- LayerNorm (adds residual states here, coalesced) ----------------
__global__ __launch_bounds__(256)
void ln_kernel(const float* __restrict__ y, const unsigned short* __restrict__ statesb,
               const float* __restrict__ gamma, const float* __restrict__ beta,
               float* __restrict__ out)
{
  const int row = blockIdx.x;
  const int tid = threadIdx.x;
  float4 v = ((const float4*)(y + (size_t)row*D_MODEL))[tid];
  ushort4 sb = ((const ushort4*)(statesb + (size_t)row*D_MODEL))[tid];
  v.x += bf2f(sb.x); v.y += bf2f(sb.y); v.z += bf2f(sb.z); v.w += bf2f(sb.w);
  float s = v.x+v.y+v.z+v.w;
  float q = v.x*v.x + v.y*v.y + v.z*v.z + v.w*v.w;
  #pragma unroll
  for (int off=32; off>0; off>>=1){ s += __shfl_xor(s, off); q += __shfl_xor(q, off); }
  __shared__ float rs[4], rq[4];
  const int wave = tid>>6, lane = tid&63;
  if (lane==0){ rs[wave]=s; rq[wave]=q; }
  __syncthreads();
  float ts = rs[0]+rs[1]+rs[2]+rs[3];
  float tq = rq[0]+rq[1]+rq[2]+rq[3];
  float mu  = ts * (1.f/D_MODEL);
  float var = tq * (1.f/D_MODEL) - mu*mu;
  float inv = rsqrtf(var + 1e-5f);
  float4 g = ((const float4*)gamma)[tid];
  float4 b = ((const float4*)beta)[tid];
  float4 o;
  o.x = (v.x-mu)*inv*g.x + b.x;
  o.y = (v.y-mu)*inv*g.y + b.y;
  o.z = (v.z-mu)*inv*g.z + b.z;
  o.w = (v.w-mu)*inv*g.w + b.w;
  ((float4*)(out + (size_t)row*D_MODEL))[tid] = o;
}

extern "C" void kernel_launch(void* const* d_in, const int* in_sizes, int n_in,
                              void* d_out, int out_size, void* d_ws, size_t ws_size,
                              hipStream_t stream) {
  const float* x         = (const float*)d_in[0];
  const float* delta     = (const float*)d_in[1];
  const float* log_decay = (const float*)d_in[2];
  const float* W_in      = (const float*)d_in[3];
  const float* b_in      = (const float*)d_in[4];
  const float* W_gate    = (const float*)d_in[5];
  const float* b_gate    = (const float*)d_in[6];
  const float* W_out     = (const float*)d_in[7];
  const float* b_out     = (const float*)d_in[8];
  const float* gamma     = (const float*)d_in[9];
  const float* beta      = (const float*)d_in[10];

  char* w = (char*)d_ws;
  unsigned short* xb   = (unsigned short*)(w);                 // 64 MiB, reused as statesb
  unsigned short* Wib  = (unsigned short*)(w + 67108864);      // 2 MiB
  unsigned short* Wgb  = (unsigned short*)(w + 69206016);      // 2 MiB
  unsigned short* Wob  = (unsigned short*)(w + 71303168);      // 2 MiB
  float*          decay= (float*)        (w + 73400320);       // 4 KiB
  float*          cA   = (float*)        (w + 73404416);       // 2 MiB
  float*          cB   = (float*)        (w + 75501568);       // 2 MiB
  float*          cS   = (float*)        (w + 77598720);       // 2 MiB
  unsigned int*   pack = (unsigned int*) (w + 79695872);       // 128 MiB, reused as y
  float*          ybuf = (float*)pack;
  unsigned short* statesb = xb;

  float* out    = (float*)d_out;
  float* fstate = out + (size_t)MROWS*D_MODEL;
  // first half of d_out is dead until ln_kernel -> use as bf16 u scratch
  unsigned short* ub = (unsigned short*)d_out;

  hipLaunchKernelGGL(prep_x_kernel, dim3(8192), dim3(256), 0, stream, x, xb, MROWS*D_MODEL/4);
  hipLaunchKernelGGL(prep_w_kernel, dim3(1024), dim3(256), 0, stream,
                     W_in, W_gate, W_out, log_decay, Wib, Wgb, Wob, decay);
  gemm8_kernel<0><<<dim3(512), dim3(512), 0, stream>>>(
      xb, Wib, b_in, nullptr, nullptr, nullptr, ub, nullptr, nullptr);
  gemm8_kernel<1><<<dim3(512), dim3(512), 0, stream>>>(
      xb, Wgb, b_gate, decay, delta, ub, nullptr, pack, nullptr);
  hipLaunchKernelGGL(scan_passA, dim3(2,NC,BATCH), dim3(256), 0, stream, pack, cA, cB);
  hipLaunchKernelGGL(scan_passB, dim3(2,BATCH), dim3(256), 0, stream, cA, cB, cS, fstate);
  hipLaunchKernelGGL(scan_passC, dim3(2,NC,BATCH), dim3(256), 0, stream, pack, cS, statesb);
  gemm8_kernel<2><<<dim3(512), dim3(512), 0, stream>>>(
      statesb, Wob, b_out, nullptr, nullptr, nullptr, nullptr, nullptr, ybuf);
  hipLaunchKernelGGL(ln_kernel, dim3(MROWS), dim3(256), 0, stream, ybuf, statesb, gamma, beta, out);
}

// Round 4
// 588.743 us; speedup vs baseline: 1.1628x; 1.1628x over previous
//
#include <hip/hip_runtime.h>
#include <hip/hip_bf16.h>

#define D_MODEL 1024
#define BATCH 8
#define SEQ 4096
#define MROWS (BATCH*SEQ)   // 32768
#define NC 64               // number of scan chunks
#define CL 64               // chunk length (NC*CL == SEQ)

typedef __attribute__((ext_vector_type(4))) float f32x4;
typedef __attribute__((ext_vector_type(8))) short s16x8;

__device__ __forceinline__ unsigned short f2bf(float f){
  union { float f; unsigned int u; } v; v.f = f;
  return (unsigned short)((v.u + 0x7fffu + ((v.u >> 16) & 1u)) >> 16);
}
__device__ __forceinline__ float bf2f(unsigned int bits){
  union { unsigned int u; float f; } v; v.u = bits << 16; return v.f;
}

__device__ __forceinline__ void gload16(const void* g, void* l){
  __builtin_amdgcn_global_load_lds(
      (const __attribute__((address_space(1))) unsigned int*)g,
      (__attribute__((address_space(3))) unsigned int*)l, 16, 0, 0);
}

// ---------------- prep: x -> bf16 ----------------
__global__ __launch_bounds__(256)
void prep_x_kernel(const float* __restrict__ x, unsigned short* __restrict__ xb, int n4){
  int i = blockIdx.x*256 + threadIdx.x;
  int stride = gridDim.x*256;
  for (; i < n4; i += stride){
    float4 v = ((const float4*)x)[i];
    ushort4 o;
    o.x = f2bf(v.x); o.y = f2bf(v.y); o.z = f2bf(v.z); o.w = f2bf(v.w);
    ((ushort4*)xb)[i] = o;
  }
}

// ---------------- prep: weights -> bf16, decay ----------------
__global__ __launch_bounds__(256)
void prep_w_kernel(const float* __restrict__ Wi, const float* __restrict__ Wg,
                   const float* __restrict__ Wo, const float* __restrict__ ld,
                   unsigned short* __restrict__ Wib, unsigned short* __restrict__ Wgb,
                   unsigned short* __restrict__ Wob, float* __restrict__ decay){
  int i = blockIdx.x*256 + threadIdx.x;   // grid covers D*D/4 exactly
  {
    float4 a = ((const float4*)Wi)[i]; ushort4 o;
    o.x=f2bf(a.x); o.y=f2bf(a.y); o.z=f2bf(a.z); o.w=f2bf(a.w); ((ushort4*)Wib)[i]=o;
    a = ((const float4*)Wg)[i];
    o.x=f2bf(a.x); o.y=f2bf(a.y); o.z=f2bf(a.z); o.w=f2bf(a.w); ((ushort4*)Wgb)[i]=o;
    a = ((const float4*)Wo)[i];
    o.x=f2bf(a.x); o.y=f2bf(a.y); o.z=f2bf(a.z); o.w=f2bf(a.w); ((ushort4*)Wob)[i]=o;
  }
  if (i < D_MODEL){
    float v = ld[i];
    float sp = fmaxf(v, 0.f) + log1pf(expf(-fabsf(v)));   // stable softplus
    decay[i] = sp + 1e-4f;
  }
}

// ---------------- dual GEMM: update & gate, fused lambda/drive epilogue ----------------
// C[m][e] = sum_d X[m][d] * W[e][d].  A (X) staged via global_load_lds with
// T2 content-swizzle; B (Wi/Wg, 2 MB each, L2-resident) read per-K-step
// DIRECTLY global->VGPR as 16B fragments -> 3x less LDS staging in the
// barrier-drain path (the m97-structure stall).
__global__ __launch_bounds__(256, 2)
void gemm_dual_kernel(const unsigned short* __restrict__ Xb,
                      const unsigned short* __restrict__ Wib,
                      const unsigned short* __restrict__ Wgb,
                      const float* __restrict__ b_in,
                      const float* __restrict__ b_gate,
                      const float* __restrict__ decay,
                      const float* __restrict__ delta,
                      unsigned int* __restrict__ pack)
{
  __shared__ unsigned short sA[128*64];
  const int tid  = threadIdx.x;
  const int lane = tid & 63;
  const int wave = tid >> 6;
  const int wr = wave >> 1, wc = wave & 1;
  // XCD-chunked bijective swizzle: 2048 blocks, 8 XCDs, 256 blocks/XCD.
  const int bid = blockIdx.x;
  const int swz = ((bid & 7) << 8) | (bid >> 3);
  const int bcol = (swz & 7) * 128;
  const int brow = (swz >> 3) * 128;

  const f32x4 zero = {0.f,0.f,0.f,0.f};
  f32x4 accU[4][4], accG[4][4];
  #pragma unroll
  for (int a=0;a<4;a++)
    #pragma unroll
    for (int b=0;b<4;b++){ accU[a][b]=zero; accG[a][b]=zero; }

  // per-thread B fragment base (col component added per ni)
  const int kfrag = (lane>>4)*8;

  for (int kt = 0; kt < D_MODEL/64; ++kt){
    __syncthreads();
    #pragma unroll
    for (int i=0;i<4;i++){
      const int ob = i*64 + wave*16 + (i==0?0:0) ;   // placeholder, replaced below
      (void)ob;
    }
    // stage A tile (128x64 bf16 = 16 KB): 1024 chunks of 16B, 4/thread
    #pragma unroll
    for (int i=0;i<4;i++){
      const int ob = i*256 + wave*64;          // wave-uniform 16B-unit base
      const int o  = ob + lane;
      const int r  = o >> 3;                   // row 0..127
      const int c  = ((o & 7) ^ (r & 7)) * 16; // pre-swizzled source chunk
      gload16((const char*)Xb + (size_t)(brow + r)*(D_MODEL*2) + (size_t)kt*128 + c,
              (char*)sA + (size_t)ob*16);
    }
    __syncthreads();   // drains vmcnt before s_barrier (A tile ready)
    #pragma unroll
    for (int ks=0; ks<2; ++ks){
      s16x8 bi[4], bg[4], af[4];
      #pragma unroll
      for (int ni=0; ni<4; ni++){
        const int col = bcol + wc*64 + ni*16 + (lane & 15);
        const unsigned short* bp = Wib + (size_t)col*D_MODEL + kt*64 + ks*32 + kfrag;
        const unsigned short* gp = Wgb + (size_t)col*D_MODEL + kt*64 + ks*32 + kfrag;
        bi[ni] = *(const s16x8*)bp;
        bg[ni] = *(const s16x8*)gp;
      }
      #pragma unroll
      for (int mi=0; mi<4; mi++){
        const int row = wr*64 + mi*16 + (lane & 15);
        const int chunk = (ks*4 + (lane>>4)) ^ (row & 7);
        af[mi] = *(const s16x8*)((const char*)sA + row*128 + chunk*16);
      }
      #pragma unroll
      for (int mi=0; mi<4; mi++)
        #pragma unroll
        for (int ni=0; ni<4; ni++){
          accU[mi][ni] = __builtin_amdgcn_mfma_f32_16x16x32_bf16(af[mi], bi[ni], accU[mi][ni], 0,0,0);
          accG[mi][ni] = __builtin_amdgcn_mfma_f32_16x16x32_bf16(af[mi], bg[ni], accG[mi][ni], 0,0,0);
        }
    }
  }
  // epilogue: u,g -> lambda/drive, packed bf16x2 {drive(hi), 1-lambda(lo)}
  #pragma unroll
  for (int ni=0; ni<4; ni++){
    const int col = bcol + wc*64 + ni*16 + (lane & 15);
    const float vb = b_in[col], vg = b_gate[col], dc = decay[col];
    #pragma unroll
    for (int mi=0; mi<4; mi++){
      #pragma unroll
      for (int q=0; q<4; q++){
        const int row = brow + wr*64 + mi*16 + ((lane>>4)*4) + q;
        const size_t idx = (size_t)row*D_MODEL + col;
        float u = accU[mi][ni][q] + vb;
        float z = accG[mi][ni][q] + vg;
        float g = 1.f/(1.f + __expf(-z));
        float dt = fmaxf(delta[idx], 1e-4f);
        float lam = __expf(-dc*dt);
        float omla = 1.f - lam;
        float drv = omla * g * u;
        pack[idx] = ((unsigned int)f2bf(drv) << 16) | (unsigned int)f2bf(omla);
      }
    }
  }
}

// ---------------- scan pass A: per-chunk (A = prod lam, B = local scan) ----------------
__global__ __launch_bounds__(256)
void scan_passA(const unsigned int* __restrict__ pack, float* __restrict__ cA, float* __restrict__ cB){
  const int d0 = (blockIdx.x*256 + threadIdx.x)*2;   // gridDim.x = D/512 = 2
  const int c = blockIdx.y, b = blockIdx.z;
  size_t base = ((size_t)b*SEQ + (size_t)c*CL)*D_MODEL + d0;
  float A0=1.f, A1=1.f, s0=0.f, s1=0.f;
  #pragma unroll 8
  for (int t=0;t<CL;t++){
    uint2 p = *(const uint2*)(pack + base + (size_t)t*D_MODEL);
    float om0 = bf2f(p.x & 0xffffu), dr0 = bf2f(p.x >> 16);
    float om1 = bf2f(p.y & 0xffffu), dr1 = bf2f(p.y >> 16);
    float l0 = 1.f - om0, l1 = 1.f - om1;
    A0 *= l0; A1 *= l1;
    s0 = fmaf(l0, s0, dr0);
    s1 = fmaf(l1, s1, dr1);
  }
  const size_t ci = ((size_t)b*NC + c)*D_MODEL + d0;
  *(float2*)(cA+ci) = make_float2(A0,A1);
  *(float2*)(cB+ci) = make_float2(s0,s1);
}

// ---------------- scan pass B: sequential chunk combine + final_state ----------------
__global__ __launch_bounds__(256)
void scan_passB(const float* __restrict__ cA, const float* __restrict__ cB,
                float* __restrict__ cS, float* __restrict__ fstate){
  const int d0 = (blockIdx.x*256 + threadIdx.x)*2;  // gridDim.x = 2
  const int b = blockIdx.y;
  float s0=0.f, s1=0.f;
  for (int c=0;c<NC;c++){
    const size_t ci = ((size_t)b*NC + c)*D_MODEL + d0;
    *(float2*)(cS+ci) = make_float2(s0,s1);
    float2 a  = *(const float2*)(cA+ci);
    float2 bb = *(const float2*)(cB+ci);
    s0 = fmaf(a.x, s0, bb.x);
    s1 = fmaf(a.y, s1, bb.y);
  }
  *(float2*)(fstate + (size_t)b*D_MODEL + d0) = make_float2(s0,s1);
}

// ---------------- scan pass C: re-scan chunks, emit states (bf16) ----------------
__global__ __launch_bounds__(256)
void scan_passC(const unsigned int* __restrict__ pack, const float* __restrict__ cS,
                unsigned short* __restrict__ statesb){
  const int d0 = (blockIdx.x*256 + threadIdx.x)*2;
  const int c = blockIdx.y, b = blockIdx.z;
  float2 sv = *(const float2*)(cS + ((size_t)b*NC + c)*D_MODEL + d0);
  float s0 = sv.x, s1 = sv.y;
  size_t base = ((size_t)b*SEQ + (size_t)c*CL)*D_MODEL + d0;
  #pragma unroll 8
  for (int t=0;t<CL;t++){
    uint2 p = *(const uint2*)(pack + base + (size_t)t*D_MODEL);
    float om0 = bf2f(p.x & 0xffffu), dr0 = bf2f(p.x >> 16);
    float om1 = bf2f(p.y & 0xffffu), dr1 = bf2f(p.y >> 16);
    s0 = fmaf(-om0, s0, s0) + dr0;   // s = (1-om)*s + dr, decay-precise
    s1 = fmaf(-om1, s1, s1) + dr1;
    unsigned int w = ((unsigned int)f2bf(s1) << 16) | (unsigned int)f2bf(s0);
    *(unsigned int*)(statesb + base + (size_t)t*D_MODEL) = w;
  }
}

// ---------------- GEMM out: y(bf16) = states @ W_out^T + b_out ----------------
__global__ __launch_bounds__(256, 3)
void gemm_out_kernel(const unsigned short* __restrict__ Sb,
                     const unsigned short* __restrict__ Wob,
                     const float* __restrict__ b_out,
                     unsigned short* __restrict__ yb)
{
  __shared__ unsigned short sA[128*64];
  const int tid  = threadIdx.x;
  const int lane = tid & 63;
  const int wave = tid >> 6;
  const int wr = wave >> 1, wc = wave & 1;
  const int bid = blockIdx.x;
  const int swz = ((bid & 7) << 8) | (bid >> 3);
  const int bcol = (swz & 7) * 128;
  const int brow = (swz >> 3) * 128;

  const f32x4 zero = {0.f,0.f,0.f,0.f};
  f32x4 acc[4][4];
  #pragma unroll
  for (int a=0;a<4;a++)
    #pragma unroll
    for (int b=0;b<4;b++) acc[a][b]=zero;

  const int kfrag = (lane>>4)*8;

  for (int kt = 0; kt < D_MODEL/64; ++kt){
    __syncthreads();
    #pragma unroll
    for (int i=0;i<4;i++){
      const int ob = i*256 + wave*64;
      const int o  = ob + lane;
      const int r  = o >> 3;
      const int c  = ((o & 7) ^ (r & 7)) * 16;
      gload16((const char*)Sb + (size_t)(brow + r)*(D_MODEL*2) + (size_t)kt*128 + c,
              (char*)sA + (size_t)ob*16);
    }
    __syncthreads();
    #pragma unroll
    for (int ks=0; ks<2; ++ks){
      s16x8 bf[4], af[4];
      #pragma unroll
      for (int ni=0; ni<4; ni++){
        const int col = bcol + wc*64 + ni*16 + (lane & 15);
        bf[ni] = *(const s16x8*)(Wob + (size_t)col*D_MODEL + kt*64 + ks*32 + kfrag);
      }
      #pragma unroll
      for (int mi=0; mi<4; mi++){
        const int row = wr*64 + mi*16 + (lane & 15);
        const int chunk = (ks*4 + (lane>>4)) ^ (row & 7);
        af[mi] = *(const s16x8*)((const char*)sA + row*128 + chunk*16);
      }
      #pragma unroll
      for (int mi=0; mi<4; mi++)
        #pragma unroll
        for (int ni=0; ni<4; ni++)
          acc[mi][ni] = __builtin_amdgcn_mfma_f32_16x16x32_bf16(af[mi], bf[ni], acc[mi][ni], 0,0,0);
    }
  }
  #pragma unroll
  for (int ni=0; ni<4; ni++){
    const int col = bcol + wc*64 + ni*16 + (lane & 15);
    const float vb = b_out[col];
    #pragma unroll
    for (int mi=0; mi<4; mi++){
      #pragma unroll
      for (int q=0; q<4; q++){
        const int row = brow + wr*64 + mi*16 + ((lane>>4)*4) + q;
        const size_t idx = (size_t)row*D_MODEL + col;
        yb[idx] = f2bf(acc[mi][ni][q] + vb);
      }
    }
  }
}

// ---------------- LayerNorm (adds residual states, y is bf16) ----------------
__global__ __launch_bounds__(256)
void ln_kernel(const unsigned short* __restrict__ yb, const unsigned short* __restrict__ statesb,
               const float* __restrict__ gamma, const float* __restrict__ beta,
               float* __restrict__ out)
{
  const int row = blockIdx.x;
  const int tid = threadIdx.x;
  ushort4 yv = ((const ushort4*)(yb + (size_t)row*D_MODEL))[tid];
  ushort4 sb = ((const ushort4*)(statesb + (size_t)row*D_MODEL))[tid];
  float4 v;
  v.x = bf2f(yv.x) + bf2f(sb.x);
  v.y = bf2f(yv.y) + bf2f(sb.y);
  v.z = bf2f(yv.z) + bf2f(sb.z);
  v.w = bf2f(yv.w) + bf2f(sb.w);
  float s = v.x+v.y+v.z+v.w;
  float q = v.x*v.x + v.y*v.y + v.z*v.z + v.w*v.w;
  #pragma unroll
  for (int off=32; off>0; off>>=1){ s += __shfl_xor(s, off); q += __shfl_xor(q, off); }
  __shared__ float rs[4], rq[4];
  const int wave = tid>>6, lane = tid&63;
  if (lane==0){ rs[wave]=s; rq[wave]=q; }
  __syncthreads();
  float ts = rs[0]+rs[1]+rs[2]+rs[3];
  float tq = rq[0]+rq[1]+rq[2]+rq[3];
  float mu  = ts * (1.f/D_MODEL);
  float var = tq * (1.f/D_MODEL) - mu*mu;
  float inv = rsqrtf(var + 1e-5f);
  float4 g = ((const float4*)gamma)[tid];
  float4 b = ((const float4*)beta)[tid];
  float4 o;
  o.x = (v.x-mu)*inv*g.x + b.x;
  o.y = (v.y-mu)*inv*g.y + b.y;
  o.z = (v.z-mu)*inv*g.z + b.z;
  o.w = (v.w-mu)*inv*g.w + b.w;
  ((float4*)(out + (size_t)row*D_MODEL))[tid] = o;
}

extern "C" void kernel_launch(void* const* d_in, const int* in_sizes, int n_in,
                              void* d_out, int out_size, void* d_ws, size_t ws_size,
                              hipStream_t stream) {
  const float* x         = (const float*)d_in[0];
  const float* delta     = (const float*)d_in[1];
  const float* log_decay = (const float*)d_in[2];
  const float* W_in      = (const float*)d_in[3];
  const float* b_in      = (const float*)d_in[4];
  const float* W_gate    = (const float*)d_in[5];
  const float* b_gate    = (const float*)d_in[6];
  const float* W_out     = (const float*)d_in[7];
  const float* b_out     = (const float*)d_in[8];
  const float* gamma     = (const float*)d_in[9];
  const float* beta      = (const float*)d_in[10];

  char* w = (char*)d_ws;
  unsigned short* xb   = (unsigned short*)(w);                 // 64 MiB, reused as statesb
  unsigned short* Wib  = (unsigned short*)(w + 67108864);      // 2 MiB
  unsigned short* Wgb  = (unsigned short*)(w + 69206016);      // 2 MiB
  unsigned short* Wob  = (unsigned short*)(w + 71303168);      // 2 MiB
  float*          decay= (float*)        (w + 73400320);       // 4 KiB
  float*          cA   = (float*)        (w + 73404416);       // 2 MiB
  float*          cB   = (float*)        (w + 75501568);       // 2 MiB
  float*          cS   = (float*)        (w + 77598720);       // 2 MiB
  unsigned int*   pack = (unsigned int*) (w + 79695872);       // 128 MiB, reused as y(bf16)
  unsigned short* ybuf = (unsigned short*)pack;
  unsigned short* statesb = xb;

  float* out    = (float*)d_out;
  float* fstate = out + (size_t)MROWS*D_MODEL;

  hipLaunchKernelGGL(prep_x_kernel, dim3(8192), dim3(256), 0, stream, x, xb, MROWS*D_MODEL/4);
  hipLaunchKernelGGL(prep_w_kernel, dim3(1024), dim3(256), 0, stream,
                     W_in, W_gate, W_out, log_decay, Wib, Wgb, Wob, decay);
  hipLaunchKernelGGL(gemm_dual_kernel, dim3(2048), dim3(256), 0, stream,
                     xb, Wib, Wgb, b_in, b_gate, decay, delta, pack);
  hipLaunchKernelGGL(scan_passA, dim3(2,NC,BATCH), dim3(256), 0, stream, pack, cA, cB);
  hipLaunchKernelGGL(scan_passB, dim3(2,BATCH), dim3(256), 0, stream, cA, cB, cS, fstate);
  hipLaunchKernelGGL(scan_passC, dim3(2,NC,BATCH), dim3(256), 0, stream, pack, cS, statesb);
  hipLaunchKernelGGL(gemm_out_kernel, dim3(2048), dim3(256), 0, stream, statesb, Wob, b_out, ybuf);
  hipLaunchKernelGGL(ln_kernel, dim3(MROWS), dim3(256), 0, stream, ybuf, statesb, gamma, beta, out);
}

// Round 5
// 545.560 us; speedup vs baseline: 1.2548x; 1.0792x over previous
//
#include <hip/hip_runtime.h>
#include <hip/hip_bf16.h>

#define D_MODEL 1024
#define BATCH 8
#define SEQ 4096
#define MROWS (BATCH*SEQ)   // 32768
#define NC 64               // number of scan chunks
#define CL 64               // chunk length (NC*CL == SEQ)

typedef __attribute__((ext_vector_type(4))) float f32x4;
typedef __attribute__((ext_vector_type(8))) short s16x8;

__device__ __forceinline__ unsigned short f2bf(float f){
  union { float f; unsigned int u; } v; v.f = f;
  return (unsigned short)((v.u + 0x7fffu + ((v.u >> 16) & 1u)) >> 16);
}
__device__ __forceinline__ float bf2f(unsigned int bits){
  union { unsigned int u; float f; } v; v.u = bits << 16; return v.f;
}

__device__ __forceinline__ void gload16(const void* g, void* l){
  __builtin_amdgcn_global_load_lds(
      (const __attribute__((address_space(1))) unsigned int*)g,
      (__attribute__((address_space(3))) unsigned int*)l, 16, 0, 0);
}

// ---------------- prep: x -> bf16 ----------------
__global__ __launch_bounds__(256)
void prep_x_kernel(const float* __restrict__ x, unsigned short* __restrict__ xb, int n4){
  int i = blockIdx.x*256 + threadIdx.x;
  int stride = gridDim.x*256;
  for (; i < n4; i += stride){
    float4 v = ((const float4*)x)[i];
    ushort4 o;
    o.x = f2bf(v.x); o.y = f2bf(v.y); o.z = f2bf(v.z); o.w = f2bf(v.w);
    ((ushort4*)xb)[i] = o;
  }
}

// ---------------- prep: weights -> bf16, decay ----------------
__global__ __launch_bounds__(256)
void prep_w_kernel(const float* __restrict__ Wi, const float* __restrict__ Wg,
                   const float* __restrict__ Wo, const float* __restrict__ ld,
                   unsigned short* __restrict__ Wib, unsigned short* __restrict__ Wgb,
                   unsigned short* __restrict__ Wob, float* __restrict__ decay){
  int i = blockIdx.x*256 + threadIdx.x;   // grid covers D*D/4 exactly
  {
    float4 a = ((const float4*)Wi)[i]; ushort4 o;
    o.x=f2bf(a.x); o.y=f2bf(a.y); o.z=f2bf(a.z); o.w=f2bf(a.w); ((ushort4*)Wib)[i]=o;
    a = ((const float4*)Wg)[i];
    o.x=f2bf(a.x); o.y=f2bf(a.y); o.z=f2bf(a.z); o.w=f2bf(a.w); ((ushort4*)Wgb)[i]=o;
    a = ((const float4*)Wo)[i];
    o.x=f2bf(a.x); o.y=f2bf(a.y); o.z=f2bf(a.z); o.w=f2bf(a.w); ((ushort4*)Wob)[i]=o;
  }
  if (i < D_MODEL){
    float v = ld[i];
    float sp = fmaxf(v, 0.f) + log1pf(expf(-fabsf(v)));   // stable softplus
    decay[i] = sp + 1e-4f;
  }
}

// ============ single 128x128 GEMM, m97 structure (2 LDS streams, 3 blk/CU) ============
// C[m][e] = sum_d A[m][d] * B[e][d]  (B^T layout)
// MODE 0: write bf16(acc + bias)            (u-pass / out-pass)
// MODE 1: read ubr+delta -> pack lambda/drive (g-pass)
template<int MODE>
__global__ __launch_bounds__(256, 3)
void gemm1_kernel(const unsigned short* __restrict__ Aglob,
                  const unsigned short* __restrict__ Bglob,
                  const float* __restrict__ bias,
                  const float* __restrict__ decay,
                  const float* __restrict__ delta,
                  const unsigned short* __restrict__ ubr,
                  unsigned short* __restrict__ ubw,
                  unsigned int* __restrict__ pack)
{
  __shared__ unsigned short sA[128*64];
  __shared__ unsigned short sB[128*64];
  const int tid  = threadIdx.x;
  const int lane = tid & 63;
  const int wave = tid >> 6;
  const int wr = wave >> 1, wc = wave & 1;
  // XCD-chunked bijective swizzle: 2048 blocks, 8 XCDs, 256 blocks/XCD.
  const int bid = blockIdx.x;
  const int swz = ((bid & 7) << 8) | (bid >> 3);
  const int bcol = (swz & 7) * 128;
  const int brow = (swz >> 3) * 128;

  const f32x4 zero = {0.f,0.f,0.f,0.f};
  f32x4 acc[4][4];
  #pragma unroll
  for (int a=0;a<4;a++)
    #pragma unroll
    for (int b=0;b<4;b++) acc[a][b]=zero;

  for (int kt = 0; kt < D_MODEL/64; ++kt){
    __syncthreads();
    // stage A and B tiles (each 128x64 bf16 = 16 KB): 4+4 gload16/thread,
    // T2 content-swizzle via pre-swizzled global source chunk (rule #21).
    #pragma unroll
    for (int i=0;i<4;i++){
      const int ob = i*256 + wave*64;          // wave-uniform 16B-unit base
      const int o  = ob + lane;
      const int r  = o >> 3;                   // row 0..127
      const int c  = ((o & 7) ^ (r & 7)) * 16;
      gload16((const char*)Aglob + (size_t)(brow + r)*(D_MODEL*2) + (size_t)kt*128 + c,
              (char*)sA + (size_t)ob*16);
      gload16((const char*)Bglob + (size_t)(bcol + r)*(D_MODEL*2) + (size_t)kt*128 + c,
              (char*)sB + (size_t)ob*16);
    }
    __syncthreads();   // compiler drains vmcnt before s_barrier
    #pragma unroll
    for (int ks=0; ks<2; ++ks){
      s16x8 af[4], bf[4];
      #pragma unroll
      for (int mi=0; mi<4; mi++){
        const int row = wr*64 + mi*16 + (lane & 15);
        const int chunk = (ks*4 + (lane>>4)) ^ (row & 7);
        af[mi] = *(const s16x8*)((const char*)sA + row*128 + chunk*16);
      }
      #pragma unroll
      for (int ni=0; ni<4; ni++){
        const int n = wc*64 + ni*16 + (lane & 15);
        const int chunk = (ks*4 + (lane>>4)) ^ (n & 7);
        bf[ni] = *(const s16x8*)((const char*)sB + n*128 + chunk*16);
      }
      #pragma unroll
      for (int mi=0; mi<4; mi++)
        #pragma unroll
        for (int ni=0; ni<4; ni++)
          acc[mi][ni] = __builtin_amdgcn_mfma_f32_16x16x32_bf16(af[mi], bf[ni], acc[mi][ni], 0,0,0);
    }
  }

  #pragma unroll
  for (int ni=0; ni<4; ni++){
    const int col = bcol + wc*64 + ni*16 + (lane & 15);
    const float vb = bias[col];
    float dc = 0.f;
    if constexpr (MODE==1) dc = decay[col];
    #pragma unroll
    for (int mi=0; mi<4; mi++){
      #pragma unroll
      for (int q=0; q<4; q++){
        const int row = brow + wr*64 + mi*16 + ((lane>>4)*4) + q;
        const size_t idx = (size_t)row*D_MODEL + col;
        const float v = acc[mi][ni][q] + vb;
        if constexpr (MODE==0){
          ubw[idx] = f2bf(v);
        } else {
          const float u = bf2f((unsigned int)ubr[idx]);
          const float g = 1.f/(1.f + __expf(-v));
          const float dt = fmaxf(delta[idx], 1e-4f);
          const float lam = __expf(-dc*dt);
          const float omla = 1.f - lam;
          const float drv = omla * g * u;
          pack[idx] = ((unsigned int)f2bf(drv) << 16) | (unsigned int)f2bf(omla);
        }
      }
    }
  }
}

// ---------------- scan pass A: per-chunk (A = prod lam, B = local scan) ----------------
__global__ __launch_bounds__(256)
void scan_passA(const unsigned int* __restrict__ pack, float* __restrict__ cA, float* __restrict__ cB){
  const int d0 = (blockIdx.x*256 + threadIdx.x)*2;   // gridDim.x = D/512 = 2
  const int c = blockIdx.y, b = blockIdx.z;
  size_t base = ((size_t)b*SEQ + (size_t)c*CL)*D_MODEL + d0;
  float A0=1.f, A1=1.f, s0=0.f, s1=0.f;
  #pragma unroll 8
  for (int t=0;t<CL;t++){
    uint2 p = *(const uint2*)(pack + base + (size_t)t*D_MODEL);
    float om0 = bf2f(p.x & 0xffffu), dr0 = bf2f(p.x >> 16);
    float om1 = bf2f(p.y & 0xffffu), dr1 = bf2f(p.y >> 16);
    float l0 = 1.f - om0, l1 = 1.f - om1;
    A0 *= l0; A1 *= l1;
    s0 = fmaf(l0, s0, dr0);
    s1 = fmaf(l1, s1, dr1);
  }
  const size_t ci = ((size_t)b*NC + c)*D_MODEL + d0;
  *(float2*)(cA+ci) = make_float2(A0,A1);
  *(float2*)(cB+ci) = make_float2(s0,s1);
}

// ---------------- scan pass B: sequential chunk combine + final_state ----------------
__global__ __launch_bounds__(256)
void scan_passB(const float* __restrict__ cA, const float* __restrict__ cB,
                float* __restrict__ cS, float* __restrict__ fstate){
  const int d0 = (blockIdx.x*256 + threadIdx.x)*2;  // gridDim.x = 2
  const int b = blockIdx.y;
  float s0=0.f, s1=0.f;
  for (int c=0;c<NC;c++){
    const size_t ci = ((size_t)b*NC + c)*D_MODEL + d0;
    *(float2*)(cS+ci) = make_float2(s0,s1);
    float2 a  = *(const float2*)(cA+ci);
    float2 bb = *(const float2*)(cB+ci);
    s0 = fmaf(a.x, s0, bb.x);
    s1 = fmaf(a.y, s1, bb.y);
  }
  *(float2*)(fstate + (size_t)b*D_MODEL + d0) = make_float2(s0,s1);
}

// ---------------- scan pass C: re-scan chunks, emit states (bf16) ----------------
__global__ __launch_bounds__(256)
void scan_passC(const unsigned int* __restrict__ pack, const float* __restrict__ cS,
                unsigned short* __restrict__ statesb){
  const int d0 = (blockIdx.x*256 + threadIdx.x)*2;
  const int c = blockIdx.y, b = blockIdx.z;
  float2 sv = *(const float2*)(cS + ((size_t)b*NC + c)*D_MODEL + d0);
  float s0 = sv.x, s1 = sv.y;
  size_t base = ((size_t)b*SEQ + (size_t)c*CL)*D_MODEL + d0;
  #pragma unroll 8
  for (int t=0;t<CL;t++){
    uint2 p = *(const uint2*)(pack + base + (size_t)t*D_MODEL);
    float om0 = bf2f(p.x & 0xffffu), dr0 = bf2f(p.x >> 16);
    float om1 = bf2f(p.y & 0xffffu), dr1 = bf2f(p.y >> 16);
    s0 = fmaf(-om0, s0, s0) + dr0;   // s = (1-om)*s + dr, decay-precise
    s1 = fmaf(-om1, s1, s1) + dr1;
    unsigned int w = ((unsigned int)f2bf(s1) << 16) | (unsigned int)f2bf(s0);
    *(unsigned int*)(statesb + base + (size_t)t*D_MODEL) = w;
  }
}

// ---------------- LayerNorm (adds residual states, y is bf16) ----------------
__global__ __launch_bounds__(256)
void ln_kernel(const unsigned short* __restrict__ yb, const unsigned short* __restrict__ statesb,
               const float* __restrict__ gamma, const float* __restrict__ beta,
               float* __restrict__ out)
{
  const int row = blockIdx.x;
  const int tid = threadIdx.x;
  ushort4 yv = ((const ushort4*)(yb + (size_t)row*D_MODEL))[tid];
  ushort4 sb = ((const ushort4*)(statesb + (size_t)row*D_MODEL))[tid];
  float4 v;
  v.x = bf2f(yv.x) + bf2f(sb.x);
  v.y = bf2f(yv.y) + bf2f(sb.y);
  v.z = bf2f(yv.z) + bf2f(sb.z);
  v.w = bf2f(yv.w) + bf2f(sb.w);
  float s = v.x+v.y+v.z+v.w;
  float q = v.x*v.x + v.y*v.y + v.z*v.z + v.w*v.w;
  #pragma unroll
  for (int off=32; off>0; off>>=1){ s += __shfl_xor(s, off); q += __shfl_xor(q, off); }
  __shared__ float rs[4], rq[4];
  const int wave = tid>>6, lane = tid&63;
  if (lane==0){ rs[wave]=s; rq[wave]=q; }
  __syncthreads();
  float ts = rs[0]+rs[1]+rs[2]+rs[3];
  float tq = rq[0]+rq[1]+rq[2]+rq[3];
  float mu  = ts * (1.f/D_MODEL);
  float var = tq * (1.f/D_MODEL) - mu*mu;
  float inv = rsqrtf(var + 1e-5f);
  float4 g = ((const float4*)gamma)[tid];
  float4 b = ((const float4*)beta)[tid];
  float4 o;
  o.x = (v.x-mu)*inv*g.x + b.x;
  o.y = (v.y-mu)*inv*g.y + b.y;
  o.z = (v.z-mu)*inv*g.z + b.z;
  o.w = (v.w-mu)*inv*g.w + b.w;
  ((float4*)(out + (size_t)row*D_MODEL))[tid] = o;
}

extern "C" void kernel_launch(void* const* d_in, const int* in_sizes, int n_in,
                              void* d_out, int out_size, void* d_ws, size_t ws_size,
                              hipStream_t stream) {
  const float* x         = (const float*)d_in[0];
  const float* delta     = (const float*)d_in[1];
  const float* log_decay = (const float*)d_in[2];
  const float* W_in      = (const float*)d_in[3];
  const float* b_in      = (const float*)d_in[4];
  const float* W_gate    = (const float*)d_in[5];
  const float* b_gate    = (const float*)d_in[6];
  const float* W_out     = (const float*)d_in[7];
  const float* b_out     = (const float*)d_in[8];
  const float* gamma     = (const float*)d_in[9];
  const float* beta      = (const float*)d_in[10];

  char* w = (char*)d_ws;
  unsigned short* xb   = (unsigned short*)(w);                 // 64 MiB, reused as statesb
  unsigned short* Wib  = (unsigned short*)(w + 67108864);      // 2 MiB
  unsigned short* Wgb  = (unsigned short*)(w + 69206016);      // 2 MiB
  unsigned short* Wob  = (unsigned short*)(w + 71303168);      // 2 MiB
  float*          decay= (float*)        (w + 73400320);       // 4 KiB
  float*          cA   = (float*)        (w + 73404416);       // 2 MiB
  float*          cB   = (float*)        (w + 75501568);       // 2 MiB
  float*          cS   = (float*)        (w + 77598720);       // 2 MiB
  unsigned int*   pack = (unsigned int*) (w + 79695872);       // 128 MiB, reused as y(bf16)
  unsigned short* ybuf = (unsigned short*)pack;
  unsigned short* statesb = xb;

  float* out    = (float*)d_out;
  float* fstate = out + (size_t)MROWS*D_MODEL;
  // first 64 MiB of d_out is dead until ln_kernel -> bf16 u scratch
  unsigned short* ub = (unsigned short*)d_out;

  hipLaunchKernelGGL(prep_x_kernel, dim3(8192), dim3(256), 0, stream, x, xb, MROWS*D_MODEL/4);
  hipLaunchKernelGGL(prep_w_kernel, dim3(1024), dim3(256), 0, stream,
                     W_in, W_gate, W_out, log_decay, Wib, Wgb, Wob, decay);
  // u-pass: ub = bf16(X Win^T + b_in)
  gemm1_kernel<0><<<dim3(2048), dim3(256), 0, stream>>>(
      xb, Wib, b_in, nullptr, nullptr, nullptr, ub, nullptr);
  // g-pass: pack = {drive, 1-lambda}
  gemm1_kernel<1><<<dim3(2048), dim3(256), 0, stream>>>(
      xb, Wgb, b_gate, decay, delta, ub, nullptr, pack);
  hipLaunchKernelGGL(scan_passA, dim3(2,NC,BATCH), dim3(256), 0, stream, pack, cA, cB);
  hipLaunchKernelGGL(scan_passB, dim3(2,BATCH), dim3(256), 0, stream, cA, cB, cS, fstate);
  hipLaunchKernelGGL(scan_passC, dim3(2,NC,BATCH), dim3(256), 0, stream, pack, cS, statesb);
  // out-pass: ybuf = bf16(states Wout^T + b_out)
  gemm1_kernel<0><<<dim3(2048), dim3(256), 0, stream>>>(
      statesb, Wob, b_out, nullptr, nullptr, nullptr, ybuf, nullptr);
  hipLaunchKernelGGL(ln_kernel, dim3(MROWS), dim3(256), 0, stream, ybuf, statesb, gamma, beta, out);
}

// Round 6
// 416.606 us; speedup vs baseline: 1.6433x; 1.3095x over previous
//
#include <hip/hip_runtime.h>
#include <hip/hip_bf16.h>

#define D_MODEL 1024
#define BATCH 8
#define SEQ 4096
#define MROWS (BATCH*SEQ)   // 32768
#define NC 64               // number of scan chunks
#define CL 64               // chunk length (NC*CL == SEQ)

typedef __attribute__((ext_vector_type(4))) float f32x4;
typedef __attribute__((ext_vector_type(8))) short s16x8;

__device__ __forceinline__ unsigned short f2bf(float f){
  union { float f; unsigned int u; } v; v.f = f;
  return (unsigned short)((v.u + 0x7fffu + ((v.u >> 16) & 1u)) >> 16);
}
__device__ __forceinline__ float bf2f(unsigned int bits){
  union { unsigned int u; float f; } v; v.u = bits << 16; return v.f;
}

__device__ __forceinline__ void gload16(const void* g, void* l){
  __builtin_amdgcn_global_load_lds(
      (const __attribute__((address_space(1))) unsigned int*)g,
      (__attribute__((address_space(3))) unsigned int*)l, 16, 0, 0);
}

// ---------------- prep: x -> bf16 ----------------
__global__ __launch_bounds__(256)
void prep_x_kernel(const float* __restrict__ x, unsigned short* __restrict__ xb, int n4){
  int i = blockIdx.x*256 + threadIdx.x;
  int stride = gridDim.x*256;
  for (; i < n4; i += stride){
    float4 v = ((const float4*)x)[i];
    ushort4 o;
    o.x = f2bf(v.x); o.y = f2bf(v.y); o.z = f2bf(v.z); o.w = f2bf(v.w);
    ((ushort4*)xb)[i] = o;
  }
}

// ---------------- prep: weights -> bf16, decay ----------------
__global__ __launch_bounds__(256)
void prep_w_kernel(const float* __restrict__ Wi, const float* __restrict__ Wg,
                   const float* __restrict__ Wo, const float* __restrict__ ld,
                   unsigned short* __restrict__ Wib, unsigned short* __restrict__ Wgb,
                   unsigned short* __restrict__ Wob, float* __restrict__ decay){
  int i = blockIdx.x*256 + threadIdx.x;   // grid covers D*D/4 exactly
  {
    float4 a = ((const float4*)Wi)[i]; ushort4 o;
    o.x=f2bf(a.x); o.y=f2bf(a.y); o.z=f2bf(a.z); o.w=f2bf(a.w); ((ushort4*)Wib)[i]=o;
    a = ((const float4*)Wg)[i];
    o.x=f2bf(a.x); o.y=f2bf(a.y); o.z=f2bf(a.z); o.w=f2bf(a.w); ((ushort4*)Wgb)[i]=o;
    a = ((const float4*)Wo)[i];
    o.x=f2bf(a.x); o.y=f2bf(a.y); o.z=f2bf(a.z); o.w=f2bf(a.w); ((ushort4*)Wob)[i]=o;
  }
  if (i < D_MODEL){
    float v = ld[i];
    float sp = fmaxf(v, 0.f) + log1pf(expf(-fabsf(v)));   // stable softplus
    decay[i] = sp + 1e-4f;
  }
}

// ============ single 128x128 GEMM, m97 structure: C = bf16(A B^T + bias) ============
// Pure streaming GEMM: no scattered epilogue reads, bf16 output only.
__global__ __launch_bounds__(256, 3)
void gemm1_kernel(const unsigned short* __restrict__ Aglob,
                  const unsigned short* __restrict__ Bglob,
                  const float* __restrict__ bias,
                  unsigned short* __restrict__ Cout)
{
  __shared__ unsigned short sA[128*64];
  __shared__ unsigned short sB[128*64];
  const int tid  = threadIdx.x;
  const int lane = tid & 63;
  const int wave = tid >> 6;
  const int wr = wave >> 1, wc = wave & 1;
  // XCD-chunked bijective swizzle: 2048 blocks, 8 XCDs, 256 blocks/XCD.
  const int bid = blockIdx.x;
  const int swz = ((bid & 7) << 8) | (bid >> 3);
  const int bcol = (swz & 7) * 128;
  const int brow = (swz >> 3) * 128;

  const f32x4 zero = {0.f,0.f,0.f,0.f};
  f32x4 acc[4][4];
  #pragma unroll
  for (int a=0;a<4;a++)
    #pragma unroll
    for (int b=0;b<4;b++) acc[a][b]=zero;

  for (int kt = 0; kt < D_MODEL/64; ++kt){
    __syncthreads();
    // stage A and B tiles (each 128x64 bf16 = 16 KB): 4+4 gload16/thread,
    // T2 content-swizzle via pre-swizzled global source chunk (rule #21).
    #pragma unroll
    for (int i=0;i<4;i++){
      const int ob = i*256 + wave*64;          // wave-uniform 16B-unit base
      const int o  = ob + lane;
      const int r  = o >> 3;                   // row 0..127
      const int c  = ((o & 7) ^ (r & 7)) * 16;
      gload16((const char*)Aglob + (size_t)(brow + r)*(D_MODEL*2) + (size_t)kt*128 + c,
              (char*)sA + (size_t)ob*16);
      gload16((const char*)Bglob + (size_t)(bcol + r)*(D_MODEL*2) + (size_t)kt*128 + c,
              (char*)sB + (size_t)ob*16);
    }
    __syncthreads();   // compiler drains vmcnt before s_barrier
    #pragma unroll
    for (int ks=0; ks<2; ++ks){
      s16x8 af[4], bf[4];
      #pragma unroll
      for (int mi=0; mi<4; mi++){
        const int row = wr*64 + mi*16 + (lane & 15);
        const int chunk = (ks*4 + (lane>>4)) ^ (row & 7);
        af[mi] = *(const s16x8*)((const char*)sA + row*128 + chunk*16);
      }
      #pragma unroll
      for (int ni=0; ni<4; ni++){
        const int n = wc*64 + ni*16 + (lane & 15);
        const int chunk = (ks*4 + (lane>>4)) ^ (n & 7);
        bf[ni] = *(const s16x8*)((const char*)sB + n*128 + chunk*16);
      }
      #pragma unroll
      for (int mi=0; mi<4; mi++)
        #pragma unroll
        for (int ni=0; ni<4; ni++)
          acc[mi][ni] = __builtin_amdgcn_mfma_f32_16x16x32_bf16(af[mi], bf[ni], acc[mi][ni], 0,0,0);
    }
  }

  #pragma unroll
  for (int ni=0; ni<4; ni++){
    const int col = bcol + wc*64 + ni*16 + (lane & 15);
    const float vb = bias[col];
    #pragma unroll
    for (int mi=0; mi<4; mi++){
      #pragma unroll
      for (int q=0; q<4; q++){
        const int row = brow + wr*64 + mi*16 + ((lane>>4)*4) + q;
        Cout[(size_t)row*D_MODEL + col] = f2bf(acc[mi][ni][q] + vb);
      }
    }
  }
}

// ------- scan pass A (FUSED): u,g_raw,delta -> lambda/drive -> pack + chunk reduce -------
__global__ __launch_bounds__(256)
void scan_passA(const unsigned short* __restrict__ ub,
                const unsigned short* __restrict__ gb,
                const float* __restrict__ delta,
                const float* __restrict__ decay,
                unsigned int* __restrict__ pack,
                float* __restrict__ cA, float* __restrict__ cB){
  const int d0 = (blockIdx.x*256 + threadIdx.x)*2;   // gridDim.x = D/512 = 2
  const int c = blockIdx.y, b = blockIdx.z;
  const float dc0 = decay[d0], dc1 = decay[d0+1];
  size_t base = ((size_t)b*SEQ + (size_t)c*CL)*D_MODEL + d0;
  float A0=1.f, A1=1.f, s0=0.f, s1=0.f;
  #pragma unroll 4
  for (int t=0;t<CL;t++){
    const size_t idx = base + (size_t)t*D_MODEL;
    const unsigned int uu = *(const unsigned int*)(ub + idx);
    const unsigned int gg = *(const unsigned int*)(gb + idx);
    const float2 dv = *(const float2*)(delta + idx);
    const float u0 = bf2f(uu & 0xffffu), u1 = bf2f(uu >> 16);
    const float z0 = bf2f(gg & 0xffffu), z1 = bf2f(gg >> 16);
    const float g0 = 1.f/(1.f + __expf(-z0));
    const float g1 = 1.f/(1.f + __expf(-z1));
    const float lam0 = __expf(-dc0 * fmaxf(dv.x, 1e-4f));
    const float lam1 = __expf(-dc1 * fmaxf(dv.y, 1e-4f));
    const float om0 = 1.f - lam0, om1 = 1.f - lam1;
    const float dr0 = om0 * g0 * u0;
    const float dr1 = om1 * g1 * u1;
    uint2 pw;
    pw.x = ((unsigned int)f2bf(dr0) << 16) | (unsigned int)f2bf(om0);
    pw.y = ((unsigned int)f2bf(dr1) << 16) | (unsigned int)f2bf(om1);
    *(uint2*)(pack + idx) = pw;
    A0 *= lam0; A1 *= lam1;
    s0 = fmaf(lam0, s0, dr0);
    s1 = fmaf(lam1, s1, dr1);
  }
  const size_t ci = ((size_t)b*NC + c)*D_MODEL + d0;
  *(float2*)(cA+ci) = make_float2(A0,A1);
  *(float2*)(cB+ci) = make_float2(s0,s1);
}

// ---------------- scan pass B: sequential chunk combine + final_state ----------------
__global__ __launch_bounds__(256)
void scan_passB(const float* __restrict__ cA, const float* __restrict__ cB,
                float* __restrict__ cS, float* __restrict__ fstate){
  const int d0 = (blockIdx.x*256 + threadIdx.x)*2;  // gridDim.x = 2
  const int b = blockIdx.y;
  float s0=0.f, s1=0.f;
  for (int c=0;c<NC;c++){
    const size_t ci = ((size_t)b*NC + c)*D_MODEL + d0;
    *(float2*)(cS+ci) = make_float2(s0,s1);
    float2 a  = *(const float2*)(cA+ci);
    float2 bb = *(const float2*)(cB+ci);
    s0 = fmaf(a.x, s0, bb.x);
    s1 = fmaf(a.y, s1, bb.y);
  }
  *(float2*)(fstate + (size_t)b*D_MODEL + d0) = make_float2(s0,s1);
}

// ---------------- scan pass C: re-scan chunks, emit states (bf16) ----------------
__global__ __launch_bounds__(256)
void scan_passC(const unsigned int* __restrict__ pack, const float* __restrict__ cS,
                unsigned short* __restrict__ statesb){
  const int d0 = (blockIdx.x*256 + threadIdx.x)*2;
  const int c = blockIdx.y, b = blockIdx.z;
  float2 sv = *(const float2*)(cS + ((size_t)b*NC + c)*D_MODEL + d0);
  float s0 = sv.x, s1 = sv.y;
  size_t base = ((size_t)b*SEQ + (size_t)c*CL)*D_MODEL + d0;
  #pragma unroll 8
  for (int t=0;t<CL;t++){
    uint2 p = *(const uint2*)(pack + base + (size_t)t*D_MODEL);
    float om0 = bf2f(p.x & 0xffffu), dr0 = bf2f(p.x >> 16);
    float om1 = bf2f(p.y & 0xffffu), dr1 = bf2f(p.y >> 16);
    s0 = fmaf(-om0, s0, s0) + dr0;   // s = (1-om)*s + dr, decay-precise
    s1 = fmaf(-om1, s1, s1) + dr1;
    unsigned int w = ((unsigned int)f2bf(s1) << 16) | (unsigned int)f2bf(s0);
    *(unsigned int*)(statesb + base + (size_t)t*D_MODEL) = w;
  }
}

// ---------------- LayerNorm (adds residual states, y is bf16) ----------------
__global__ __launch_bounds__(256)
void ln_kernel(const unsigned short* __restrict__ yb, const unsigned short* __restrict__ statesb,
               const float* __restrict__ gamma, const float* __restrict__ beta,
               float* __restrict__ out)
{
  const int row = blockIdx.x;
  const int tid = threadIdx.x;
  ushort4 yv = ((const ushort4*)(yb + (size_t)row*D_MODEL))[tid];
  ushort4 sb = ((const ushort4*)(statesb + (size_t)row*D_MODEL))[tid];
  float4 v;
  v.x = bf2f(yv.x) + bf2f(sb.x);
  v.y = bf2f(yv.y) + bf2f(sb.y);
  v.z = bf2f(yv.z) + bf2f(sb.z);
  v.w = bf2f(yv.w) + bf2f(sb.w);
  float s = v.x+v.y+v.z+v.w;
  float q = v.x*v.x + v.y*v.y + v.z*v.z + v.w*v.w;
  #pragma unroll
  for (int off=32; off>0; off>>=1){ s += __shfl_xor(s, off); q += __shfl_xor(q, off); }
  __shared__ float rs[4], rq[4];
  const int wave = tid>>6, lane = tid&63;
  if (lane==0){ rs[wave]=s; rq[wave]=q; }
  __syncthreads();
  float ts = rs[0]+rs[1]+rs[2]+rs[3];
  float tq = rq[0]+rq[1]+rq[2]+rq[3];
  float mu  = ts * (1.f/D_MODEL);
  float var = tq * (1.f/D_MODEL) - mu*mu;
  float inv = rsqrtf(var + 1e-5f);
  float4 g = ((const float4*)gamma)[tid];
  float4 b = ((const float4*)beta)[tid];
  float4 o;
  o.x = (v.x-mu)*inv*g.x + b.x;
  o.y = (v.y-mu)*inv*g.y + b.y;
  o.z = (v.z-mu)*inv*g.z + b.z;
  o.w = (v.w-mu)*inv*g.w + b.w;
  ((float4*)(out + (size_t)row*D_MODEL))[tid] = o;
}

extern "C" void kernel_launch(void* const* d_in, const int* in_sizes, int n_in,
                              void* d_out, int out_size, void* d_ws, size_t ws_size,
                              hipStream_t stream) {
  const float* x         = (const float*)d_in[0];
  const float* delta     = (const float*)d_in[1];
  const float* log_decay = (const float*)d_in[2];
  const float* W_in      = (const float*)d_in[3];
  const float* b_in      = (const float*)d_in[4];
  const float* W_gate    = (const float*)d_in[5];
  const float* b_gate    = (const float*)d_in[6];
  const float* W_out     = (const float*)d_in[7];
  const float* b_out     = (const float*)d_in[8];
  const float* gamma     = (const float*)d_in[9];
  const float* beta      = (const float*)d_in[10];

  char* w = (char*)d_ws;
  unsigned short* xb   = (unsigned short*)(w);                 // 64 MiB, reused as statesb
  unsigned short* Wib  = (unsigned short*)(w + 67108864);      // 2 MiB
  unsigned short* Wgb  = (unsigned short*)(w + 69206016);      // 2 MiB
  unsigned short* Wob  = (unsigned short*)(w + 71303168);      // 2 MiB
  float*          decay= (float*)        (w + 73400320);       // 4 KiB
  float*          cA   = (float*)        (w + 73404416);       // 2 MiB
  float*          cB   = (float*)        (w + 75501568);       // 2 MiB
  float*          cS   = (float*)        (w + 77598720);       // 2 MiB
  unsigned int*   pack = (unsigned int*) (w + 79695872);       // 128 MiB; first half reused as y(bf16)
  unsigned short* ybuf = (unsigned short*)pack;
  unsigned short* statesb = xb;

  float* out    = (float*)d_out;
  float* fstate = out + (size_t)MROWS*D_MODEL;
  // d_out's 128 MiB output area is dead until ln_kernel -> u/g bf16 scratch
  unsigned short* ub = (unsigned short*)d_out;                    // 64 MiB
  unsigned short* gb = ub + (size_t)MROWS*D_MODEL;                // 64 MiB

  hipLaunchKernelGGL(prep_x_kernel, dim3(8192), dim3(256), 0, stream, x, xb, MROWS*D_MODEL/4);
  hipLaunchKernelGGL(prep_w_kernel, dim3(1024), dim3(256), 0, stream,
                     W_in, W_gate, W_out, log_decay, Wib, Wgb, Wob, decay);
  // u-pass: ub = bf16(X Win^T + b_in)
  hipLaunchKernelGGL(gemm1_kernel, dim3(2048), dim3(256), 0, stream, xb, Wib, b_in, ub);
  // g-pass: gb = bf16(X Wgate^T + b_gate)
  hipLaunchKernelGGL(gemm1_kernel, dim3(2048), dim3(256), 0, stream, xb, Wgb, b_gate, gb);
  // fused elementwise + chunk reduction
  hipLaunchKernelGGL(scan_passA, dim3(2,NC,BATCH), dim3(256), 0, stream,
                     ub, gb, delta, decay, pack, cA, cB);
  hipLaunchKernelGGL(scan_passB, dim3(2,BATCH), dim3(256), 0, stream, cA, cB, cS, fstate);
  hipLaunchKernelGGL(scan_passC, dim3(2,NC,BATCH), dim3(256), 0, stream, pack, cS, statesb);
  // out-pass: ybuf = bf16(states Wout^T + b_out)
  hipLaunchKernelGGL(gemm1_kernel, dim3(2048), dim3(256), 0, stream, statesb, Wob, b_out, ybuf);
  hipLaunchKernelGGL(ln_kernel, dim3(MROWS), dim3(256), 0, stream, ybuf, statesb, gamma, beta, out);
}